// Round 1
// baseline (113.828 us; speedup 1.0000x reference)
//
#include <hip/hip_runtime.h>

// Problem constants (B=2, C=3, D=64, H=128, W=128)
static constexpr int kS   = 64 * 128 * 128;  // spatial size per (b,c) = 1048576
static constexpr int kB   = 2;
static constexpr int kC   = 3;
static constexpr int kNV  = kB * kS;         // voxels over (B,D,H,W) = 2097152
static constexpr int kNV4 = kNV / 4;         // float4 groups = 524288

// dist_maps[:,1] collapses analytically to (cls != 1) ? 1 : 0 (see session
// notes): the 4D EDT over (C,D,H,W) with C=3 always finds a zero/pos voxel at
// the same spatial site one channel away (4D dist^2 == 1), and no voxel other
// than itself can be closer. The int32 truncation is a no-op on {0,1}.

__global__ __launch_bounds__(256) void loss_reduce(
    const float* __restrict__ probs,
    const float* __restrict__ target,
    double* __restrict__ acc)   // acc[0]=surf_sum acc[1]=tp acc[2]=fp acc[3]=fn
{
    int gid = blockIdx.x * blockDim.x + threadIdx.x;
    int stride = gridDim.x * blockDim.x;

    float surf = 0.f, tp = 0.f, fp = 0.f, fn = 0.f;

    for (int i = gid; i < kNV4; i += stride) {
        int v = i << 2;                  // voxel index in [0, kNV); groups never cross b
        int b = v / kS;
        int x = v - b * kS;
        size_t base = (size_t)b * kC * kS + (size_t)x;

        float4 p0 = *(const float4*)(probs + base);
        float4 p1 = *(const float4*)(probs + base + kS);
        float4 p2 = *(const float4*)(probs + base + 2 * (size_t)kS);
        float4 t0 = *(const float4*)(target + base);
        float4 t1 = *(const float4*)(target + base + kS);
        float4 t2 = *(const float4*)(target + base + 2 * (size_t)kS);

        float pa[4] = {p0.x, p0.y, p0.z, p0.w};
        float pb[4] = {p1.x, p1.y, p1.z, p1.w};
        float pc[4] = {p2.x, p2.y, p2.z, p2.w};
        float ta[4] = {t0.x, t0.y, t0.z, t0.w};
        float tb[4] = {t1.x, t1.y, t1.z, t1.w};
        float tc[4] = {t2.x, t2.y, t2.z, t2.w};

#pragma unroll
        for (int j = 0; j < 4; ++j) {
            float c0 = pa[j], c1 = pb[j], c2 = pc[j];
            // first-index argmax tie-break (strict >)
            int cls = 0; float best = c0;
            if (c1 > best) { best = c1; cls = 1; }
            if (c2 > best) { cls = 2; }
            if (cls != 1) surf += c1;    // dist_maps[:,1] == 1 here, else 0

            tp += c0 * ta[j] + c1 * tb[j] + c2 * tc[j];
            fp += (1.f - ta[j]) * c0 + (1.f - tb[j]) * c1 + (1.f - tc[j]) * c2;
            fn += ta[j] * (1.f - c0) + tb[j] * (1.f - c1) + tc[j] * (1.f - c2);
        }
    }

    // wave (64-lane) reduction in double
    double ds = surf, dtp = tp, dfp = fp, dfn = fn;
#pragma unroll
    for (int off = 32; off > 0; off >>= 1) {
        ds  += __shfl_down(ds,  off);
        dtp += __shfl_down(dtp, off);
        dfp += __shfl_down(dfp, off);
        dfn += __shfl_down(dfn, off);
    }

    __shared__ double sh[4][4];          // 4 waves per 256-thread block
    int lane = threadIdx.x & 63;
    int wave = threadIdx.x >> 6;
    if (lane == 0) {
        sh[wave][0] = ds; sh[wave][1] = dtp; sh[wave][2] = dfp; sh[wave][3] = dfn;
    }
    __syncthreads();
    if (threadIdx.x == 0) {
        double a0 = 0, a1 = 0, a2 = 0, a3 = 0;
#pragma unroll
        for (int w = 0; w < 4; ++w) {
            a0 += sh[w][0]; a1 += sh[w][1]; a2 += sh[w][2]; a3 += sh[w][3];
        }
        atomicAdd(&acc[0], a0);
        atomicAdd(&acc[1], a1);
        atomicAdd(&acc[2], a2);
        atomicAdd(&acc[3], a3);
    }
}

__global__ void loss_finalize(const double* __restrict__ acc,
                              float* __restrict__ out)
{
    double surface = acc[0] / (double)kNV;
    double tversky = 1.0 - (acc[1] + 1.0) /
                           (acc[1] + 0.5 * acc[2] + 0.5 * acc[3] + 1.0);
    out[0] = (float)(surface + tversky);
}

extern "C" void kernel_launch(void* const* d_in, const int* in_sizes, int n_in,
                              void* d_out, int out_size, void* d_ws, size_t ws_size,
                              hipStream_t stream)
{
    const float* probs  = (const float*)d_in[0];
    const float* target = (const float*)d_in[1];
    float* out = (float*)d_out;
    double* acc = (double*)d_ws;

    // zero the 4 accumulators every call (ws is poisoned once, never restored)
    hipMemsetAsync(acc, 0, 4 * sizeof(double), stream);

    // 524288 float4 groups / 256 threads = 2048 blocks, one group per thread
    loss_reduce<<<2048, 256, 0, stream>>>(probs, target, acc);
    loss_finalize<<<1, 1, 0, stream>>>(acc, out);
}

// Round 2
// 17.655 us; speedup vs baseline: 6.4474x; 6.4474x over previous
//
#include <hip/hip_runtime.h>

// Problem constants (B=2, C=3, D=64, H=128, W=128)
static constexpr int kS   = 64 * 128 * 128;  // spatial size per (b,c) = 1048576
static constexpr int kB   = 2;
static constexpr int kC   = 3;
static constexpr int kNV  = kB * kS;         // voxels over (B,D,H,W) = 2097152
static constexpr int kNV4 = kNV / 4;         // float4 groups = 524288

static constexpr int BLOCKS  = 1024;
static constexpr int THREADS = 256;          // 262144 threads -> 2 groups/thread

// dist_maps[:,1] collapses analytically to (cls != 1) ? 1 : 0: the 4D EDT over
// (C,D,H,W) with C=3 always finds a zero/pos voxel at the same spatial site
// one channel away (4D dist^2 == 1), and nothing can be closer. The int32
// truncation in the reference is a no-op on {0,1}.

__global__ __launch_bounds__(THREADS) void loss_reduce(
    const float* __restrict__ probs,
    const float* __restrict__ target,
    double* __restrict__ partials)   // [BLOCKS][4]: surf, tp, fp, fn
{
    int gid = blockIdx.x * THREADS + threadIdx.x;

    float surf = 0.f, tp = 0.f, fp = 0.f, fn = 0.f;

#pragma unroll
    for (int it = 0; it < kNV4 / (BLOCKS * THREADS); ++it) {
        int i = gid + it * (BLOCKS * THREADS);
        int v = i << 2;                  // voxel index; float4 never crosses b
        int b = v >> 20;                 // v / kS
        int x = v & (kS - 1);            // v % kS
        size_t base = (size_t)b * kC * kS + (size_t)x;

        float4 p0 = *(const float4*)(probs + base);
        float4 p1 = *(const float4*)(probs + base + kS);
        float4 p2 = *(const float4*)(probs + base + 2 * (size_t)kS);
        float4 t0 = *(const float4*)(target + base);
        float4 t1 = *(const float4*)(target + base + kS);
        float4 t2 = *(const float4*)(target + base + 2 * (size_t)kS);

        float pa[4] = {p0.x, p0.y, p0.z, p0.w};
        float pb[4] = {p1.x, p1.y, p1.z, p1.w};
        float pc[4] = {p2.x, p2.y, p2.z, p2.w};
        float ta[4] = {t0.x, t0.y, t0.z, t0.w};
        float tb[4] = {t1.x, t1.y, t1.z, t1.w};
        float tc[4] = {t2.x, t2.y, t2.z, t2.w};

#pragma unroll
        for (int j = 0; j < 4; ++j) {
            float c0 = pa[j], c1 = pb[j], c2 = pc[j];
            // first-index argmax tie-break (strict >): surface term counts c1
            // wherever argmax != 1, i.e. c0 >= c1 or c2 > max(c0,c1)
            int cls = 0; float best = c0;
            if (c1 > best) { best = c1; cls = 1; }
            if (c2 > best) { cls = 2; }
            if (cls != 1) surf += c1;

            tp += c0 * ta[j] + c1 * tb[j] + c2 * tc[j];
            fp += (1.f - ta[j]) * c0 + (1.f - tb[j]) * c1 + (1.f - tc[j]) * c2;
            fn += ta[j] * (1.f - c0) + tb[j] * (1.f - c1) + tc[j] * (1.f - c2);
        }
    }

    // wave (64-lane) reduction in double
    double ds = surf, dtp = tp, dfp = fp, dfn = fn;
#pragma unroll
    for (int off = 32; off > 0; off >>= 1) {
        ds  += __shfl_down(ds,  off);
        dtp += __shfl_down(dtp, off);
        dfp += __shfl_down(dfp, off);
        dfn += __shfl_down(dfn, off);
    }

    __shared__ double sh[4][4];          // 4 waves per block
    int lane = threadIdx.x & 63;
    int wave = threadIdx.x >> 6;
    if (lane == 0) {
        sh[wave][0] = ds; sh[wave][1] = dtp; sh[wave][2] = dfp; sh[wave][3] = dfn;
    }
    __syncthreads();
    if (threadIdx.x == 0) {
        double a0 = 0, a1 = 0, a2 = 0, a3 = 0;
#pragma unroll
        for (int w = 0; w < 4; ++w) {
            a0 += sh[w][0]; a1 += sh[w][1]; a2 += sh[w][2]; a3 += sh[w][3];
        }
        double* p = partials + (size_t)blockIdx.x * 4;
        p[0] = a0; p[1] = a1; p[2] = a2; p[3] = a3;   // plain store, no atomics
    }
}

__global__ __launch_bounds__(THREADS) void loss_finalize(
    const double* __restrict__ partials,
    float* __restrict__ out)
{
    double s = 0, tp = 0, fp = 0, fn = 0;
    for (int i = threadIdx.x; i < BLOCKS; i += THREADS) {
        const double* p = partials + (size_t)i * 4;
        s += p[0]; tp += p[1]; fp += p[2]; fn += p[3];
    }
#pragma unroll
    for (int off = 32; off > 0; off >>= 1) {
        s  += __shfl_down(s,  off);
        tp += __shfl_down(tp, off);
        fp += __shfl_down(fp, off);
        fn += __shfl_down(fn, off);
    }
    __shared__ double sh[4][4];
    int lane = threadIdx.x & 63;
    int wave = threadIdx.x >> 6;
    if (lane == 0) {
        sh[wave][0] = s; sh[wave][1] = tp; sh[wave][2] = fp; sh[wave][3] = fn;
    }
    __syncthreads();
    if (threadIdx.x == 0) {
        double a0 = 0, a1 = 0, a2 = 0, a3 = 0;
#pragma unroll
        for (int w = 0; w < 4; ++w) {
            a0 += sh[w][0]; a1 += sh[w][1]; a2 += sh[w][2]; a3 += sh[w][3];
        }
        double surface = a0 / (double)kNV;
        double tversky = 1.0 - (a1 + 1.0) / (a1 + 0.5 * a2 + 0.5 * a3 + 1.0);
        out[0] = (float)(surface + tversky);
    }
}

extern "C" void kernel_launch(void* const* d_in, const int* in_sizes, int n_in,
                              void* d_out, int out_size, void* d_ws, size_t ws_size,
                              hipStream_t stream)
{
    const float* probs  = (const float*)d_in[0];
    const float* target = (const float*)d_in[1];
    float* out = (float*)d_out;
    double* partials = (double*)d_ws;    // BLOCKS*4 doubles = 32 KB

    loss_reduce<<<BLOCKS, THREADS, 0, stream>>>(probs, target, partials);
    loss_finalize<<<1, THREADS, 0, stream>>>(partials, out);
}

// Round 3
// 16.024 us; speedup vs baseline: 7.1034x; 1.1018x over previous
//
#include <hip/hip_runtime.h>

// Problem constants (B=2, C=3, D=64, H=128, W=128)
static constexpr int kS   = 64 * 128 * 128;  // spatial size per (b,c) = 1048576
static constexpr int kB   = 2;
static constexpr int kC   = 3;
static constexpr int kNV  = kB * kS;         // voxels over (B,D,H,W) = 2097152
static constexpr int kNV4 = kNV / 4;         // float4 groups = 524288

static constexpr int BLOCKS  = 1024;
static constexpr int THREADS = 256;
static constexpr int ITERS   = kNV4 / (BLOCKS * THREADS);   // = 2

// Analytic collapses (exact):
//  * dist_maps[:,1] == (argmax_c p_c != 1) ? 1 : 0  (4D EDT over C,D,H,W with
//    C=3: a zero/pos voxel always sits one channel away at 4D dist^2 = 1).
//  * target is one-hot: t2 = 1 - t0 - t1; sum(t) = NV exactly. Hence
//    fp = sum(p) - tp, fn = NV - tp, and the Tversky denominator is
//    0.5*(sum(p) + NV) + 1 — only {surf, sum_p, tp} need accumulating,
//    and target channel 2 is never read (41.9 MB instead of 50.3 MB).

__global__ __launch_bounds__(THREADS) void loss_reduce(
    const float* __restrict__ probs,
    const float* __restrict__ target,
    double* __restrict__ partials)   // [BLOCKS][3]: surf, sum_p, tp
{
    int gid = blockIdx.x * THREADS + threadIdx.x;

    // ---- issue ALL loads up front (independent, static-indexed) ----
    float4 P0[ITERS], P1[ITERS], P2[ITERS], T0[ITERS], T1[ITERS];
#pragma unroll
    for (int it = 0; it < ITERS; ++it) {
        int i = gid + it * (BLOCKS * THREADS);
        int v = i << 2;                  // voxel index; float4 never crosses b
        int b = v >> 20;                 // v / kS
        int x = v & (kS - 1);            // v % kS
        size_t base = (size_t)b * kC * kS + (size_t)x;
        P0[it] = *(const float4*)(probs + base);
        P1[it] = *(const float4*)(probs + base + kS);
        P2[it] = *(const float4*)(probs + base + 2 * (size_t)kS);
        T0[it] = *(const float4*)(target + base);
        T1[it] = *(const float4*)(target + base + kS);
    }

    float surf = 0.f, sp = 0.f, tp = 0.f;
#pragma unroll
    for (int it = 0; it < ITERS; ++it) {
        float pa[4] = {P0[it].x, P0[it].y, P0[it].z, P0[it].w};
        float pb[4] = {P1[it].x, P1[it].y, P1[it].z, P1[it].w};
        float pc[4] = {P2[it].x, P2[it].y, P2[it].z, P2[it].w};
        float ta[4] = {T0[it].x, T0[it].y, T0[it].z, T0[it].w};
        float tb[4] = {T1[it].x, T1[it].y, T1[it].z, T1[it].w};
#pragma unroll
        for (int j = 0; j < 4; ++j) {
            float c0 = pa[j], c1 = pb[j], c2 = pc[j];
            // first-index argmax tie-break (strict >)
            int cls = 0; float best = c0;
            if (c1 > best) { best = c1; cls = 1; }
            if (c2 > best) { cls = 2; }
            if (cls != 1) surf += c1;

            sp += c0 + c1 + c2;
            // tp = p0*t0 + p1*t1 + p2*(1-t0-t1)
            tp += c2 + ta[j] * (c0 - c2) + tb[j] * (c1 - c2);
        }
    }

    // wave (64-lane) reduction in double
    double ds = surf, dsp = sp, dtp = tp;
#pragma unroll
    for (int off = 32; off > 0; off >>= 1) {
        ds  += __shfl_down(ds,  off);
        dsp += __shfl_down(dsp, off);
        dtp += __shfl_down(dtp, off);
    }

    __shared__ double sh[4][3];          // 4 waves per block
    int lane = threadIdx.x & 63;
    int wave = threadIdx.x >> 6;
    if (lane == 0) { sh[wave][0] = ds; sh[wave][1] = dsp; sh[wave][2] = dtp; }
    __syncthreads();
    if (threadIdx.x == 0) {
        double a0 = 0, a1 = 0, a2 = 0;
#pragma unroll
        for (int w = 0; w < 4; ++w) { a0 += sh[w][0]; a1 += sh[w][1]; a2 += sh[w][2]; }
        double* p = partials + (size_t)blockIdx.x * 3;
        p[0] = a0; p[1] = a1; p[2] = a2;   // plain store, no atomics
    }
}

__global__ __launch_bounds__(THREADS) void loss_finalize(
    const double* __restrict__ partials,
    float* __restrict__ out)
{
    double s = 0, sp = 0, tp = 0;
    for (int i = threadIdx.x; i < BLOCKS; i += THREADS) {
        const double* p = partials + (size_t)i * 3;
        s += p[0]; sp += p[1]; tp += p[2];
    }
#pragma unroll
    for (int off = 32; off > 0; off >>= 1) {
        s  += __shfl_down(s,  off);
        sp += __shfl_down(sp, off);
        tp += __shfl_down(tp, off);
    }
    __shared__ double sh[4][3];
    int lane = threadIdx.x & 63;
    int wave = threadIdx.x >> 6;
    if (lane == 0) { sh[wave][0] = s; sh[wave][1] = sp; sh[wave][2] = tp; }
    __syncthreads();
    if (threadIdx.x == 0) {
        double a0 = 0, a1 = 0, a2 = 0;
#pragma unroll
        for (int w = 0; w < 4; ++w) { a0 += sh[w][0]; a1 += sh[w][1]; a2 += sh[w][2]; }
        double surface = a0 / (double)kNV;
        // fp = sp - tp, fn = NV - tp  =>  denom = tp + 0.5*fp + 0.5*fn + 1
        double tversky = 1.0 - (a2 + 1.0) / (0.5 * (a1 + (double)kNV) + 1.0);
        out[0] = (float)(surface + tversky);
    }
}

extern "C" void kernel_launch(void* const* d_in, const int* in_sizes, int n_in,
                              void* d_out, int out_size, void* d_ws, size_t ws_size,
                              hipStream_t stream)
{
    const float* probs  = (const float*)d_in[0];
    const float* target = (const float*)d_in[1];
    float* out = (float*)d_out;
    double* partials = (double*)d_ws;    // BLOCKS*3 doubles = 24 KB

    loss_reduce<<<BLOCKS, THREADS, 0, stream>>>(probs, target, partials);
    loss_finalize<<<1, THREADS, 0, stream>>>(partials, out);
}